// Round 4
// baseline (3134.492 us; speedup 1.0000x reference)
//
#include <hip/hip_runtime.h>

#define BN 16384
#define TT 128
#define MM 4
#define SS 12
#define BLOCK 64

// R10: 8 lanes per series -> 2048 waves = 2 waves/SIMD (TLP hides the
// distributed LDS/DPP/fp64 latency that single-wave occupancy exposes;
// R7-R9 showed the compiler will not overlap streams within one wave).
//
// Octet layout: d = tid&7; h = d>>2 (row-half), c = d&3 (col-quad).
// Lane owns P rows [6h,6h+6) x cols [3c,3c+3).  Quads are h-uniform, so all
// quad DPP idioms (qsum butterflies, broadcasts) are unchanged. h-direction
// reductions (GEMM1 k-sum, HP) use ds_swizzle xor-4 -- register-to-register,
// no LDS scratch, no barriers anywhere in the t-loop.
// Small-M work (Su/inverse/z/G/mean) is replicated across the two halves.

// quad_perm ctrl: broadcast from sub-lane R -> R*0x55; xor1 -> 0xB1; xor2 -> 0x4E
template<int CTRL>
__device__ __forceinline__ float dpp32(float v) {
    union { int i; float f; } u, o;
    u.f = v;
    o.i = __builtin_amdgcn_update_dpp(0, u.i, CTRL, 0xF, 0xF, true);
    return o.f;
}
template<int CTRL>
__device__ __forceinline__ double dpp64(double v) {
    union { double d; int i[2]; } u, o;
    u.d = v;
    o.i[0] = __builtin_amdgcn_update_dpp(0, u.i[0], CTRL, 0xF, 0xF, true);
    o.i[1] = __builtin_amdgcn_update_dpp(0, u.i[1], CTRL, 0xF, 0xF, true);
    return o.d;
}
__device__ __forceinline__ double qsum(double v) {  // sum over the quad
    v += dpp64<0xB1>(v);
    v += dpp64<0x4E>(v);
    return v;
}
// lane <-> lane^4 exchange (flips h, keeps c). BitMode: xor=4, or=0, and=0x1F.
__device__ __forceinline__ double swz4(double v) {
    union { double d; int i[2]; } u, o;
    u.d = v;
    o.i[0] = __builtin_amdgcn_ds_swizzle(u.i[0], 0x101F);
    o.i[1] = __builtin_amdgcn_ds_swizzle(u.i[1], 0x101F);
    return o.d;
}

__global__ __launch_bounds__(BLOCK, 2) void kf_kernel(
    const float* __restrict__ inp,   // [B][T][M]
    const float* __restrict__ Fm,    // [S][S]
    const float* __restrict__ Hm,    // [M][S]
    const float* __restrict__ Qm,    // [S][S]
    const float* __restrict__ Rm,    // [M][M]
    const float* __restrict__ m0p,   // [B][S]
    const float* __restrict__ P0p,   // [B][S][S]
    float* __restrict__ outp)        // [T][B][M]
{
    __shared__ double Fd[SS * SS];
    __shared__ double Hd[MM * SS];
    __shared__ double Qd[SS * SS];
    __shared__ double Rd[MM * MM];

    const int tid   = threadIdx.x;
    const int gid   = blockIdx.x * BLOCK + tid;
    const int b     = gid >> 3;        // series (8 lanes each)
    const int d     = tid & 7;
    const int h     = d >> 2;          // row-half of P
    const int c     = d & 3;           // quad sub-lane: cols {3c..3c+2}
    const int col0  = 3 * c;
    const int hrow0 = 6 * h;           // own row base
    const int orow0 = 6 - hrow0;       // other half's row base

    for (int i = tid; i < SS * SS; i += BLOCK) {
        Fd[i] = (double)Fm[i];
        Qd[i] = (double)Qm[i];
    }
    if (tid < MM * SS) Hd[tid] = (double)Hm[tid];
    if (tid < MM * MM) Rd[tid] = (double)Rm[tid];

    // persistent per-lane state: own 6x3 tile of P (posterior at loop top)
    double P[6][3];
#pragma unroll
    for (int ii = 0; ii < 6; ++ii)
#pragma unroll
        for (int jj = 0; jj < 3; ++jj)
            P[ii][jj] = (double)P0p[b * SS * SS + (hrow0 + ii) * SS + col0 + jj];

    // full replicated mean
    double m[SS];
#pragma unroll
    for (int s = 0; s < SS; ++s) m[s] = (double)m0p[b * SS + s];

    const float* op = inp + b * (TT * MM) + c;  // own measurement stream
    float obn = op[0];

    __syncthreads();  // constants in LDS ready (once)

#pragma unroll 1
    for (int t = 0; t < TT; ++t) {
        // ---------- GEMM1: U = F * P_post, k-split across halves ----------
        // pOwn: rows hrow0+ii (kept); pOth: rows orow0+ii (sent to partner).
        double pOwn[6][3], pOth[6][3];
#pragma unroll
        for (int ii = 0; ii < 6; ++ii) {
#pragma unroll
            for (int jj = 0; jj < 3; ++jj) { pOwn[ii][jj] = 0.0; pOth[ii][jj] = 0.0; }
#pragma unroll
            for (int s = 0; s < 6; ++s) {
                double fo = Fd[(hrow0 + ii) * SS + hrow0 + s];
                double ft = Fd[(orow0 + ii) * SS + hrow0 + s];
#pragma unroll
                for (int jj = 0; jj < 3; ++jj) {
                    pOwn[ii][jj] += fo * P[s][jj];
                    pOth[ii][jj] += ft * P[s][jj];
                }
            }
        }
        // U rows [hrow0,hrow0+6) x own cols: own partial + partner's complement
        double U[6][3];
#pragma unroll
        for (int ii = 0; ii < 6; ++ii)
#pragma unroll
            for (int jj = 0; jj < 3; ++jj)
                U[ii][jj] = pOwn[ii][jj] + swz4(pOth[ii][jj]);

        // ---------- own 3 quad-rows of predicted mean: F[3c+jj,:] . m ----------
        double mvl[3];
#pragma unroll
        for (int jj = 0; jj < 3; ++jj) {
            double a = 0.0;
#pragma unroll
            for (int s = 0; s < SS; ++s) a += Fd[(col0 + jj) * SS + s] * m[s];
            mvl[jj] = a;
        }

        // ---------- GEMM2: P <- Q + U * F^T (prior, in place) ----------
        // quad all-gather of U columns via DPP broadcasts (quad is h-uniform).
#pragma unroll
        for (int ii = 0; ii < 6; ++ii)
#pragma unroll
            for (int jj = 0; jj < 3; ++jj)
                P[ii][jj] = Qd[(hrow0 + ii) * SS + col0 + jj];

        {   // source sub-lane 0: U cols 0..2
            double Uq[6][3];
#pragma unroll
            for (int ii = 0; ii < 6; ++ii)
#pragma unroll
                for (int kk = 0; kk < 3; ++kk) Uq[ii][kk] = dpp64<0x00>(U[ii][kk]);
            double fq[3][3];
#pragma unroll
            for (int jj = 0; jj < 3; ++jj)
#pragma unroll
                for (int kk = 0; kk < 3; ++kk) fq[jj][kk] = Fd[(col0 + jj) * SS + 0 + kk];
#pragma unroll
            for (int ii = 0; ii < 6; ++ii)
#pragma unroll
                for (int jj = 0; jj < 3; ++jj)
#pragma unroll
                    for (int kk = 0; kk < 3; ++kk) P[ii][jj] += Uq[ii][kk] * fq[jj][kk];
        }
        {   // source sub-lane 1: U cols 3..5
            double Uq[6][3];
#pragma unroll
            for (int ii = 0; ii < 6; ++ii)
#pragma unroll
                for (int kk = 0; kk < 3; ++kk) Uq[ii][kk] = dpp64<0x55>(U[ii][kk]);
            double fq[3][3];
#pragma unroll
            for (int jj = 0; jj < 3; ++jj)
#pragma unroll
                for (int kk = 0; kk < 3; ++kk) fq[jj][kk] = Fd[(col0 + jj) * SS + 3 + kk];
#pragma unroll
            for (int ii = 0; ii < 6; ++ii)
#pragma unroll
                for (int jj = 0; jj < 3; ++jj)
#pragma unroll
                    for (int kk = 0; kk < 3; ++kk) P[ii][jj] += Uq[ii][kk] * fq[jj][kk];
        }
        {   // source sub-lane 2: U cols 6..8
            double Uq[6][3];
#pragma unroll
            for (int ii = 0; ii < 6; ++ii)
#pragma unroll
                for (int kk = 0; kk < 3; ++kk) Uq[ii][kk] = dpp64<0xAA>(U[ii][kk]);
            double fq[3][3];
#pragma unroll
            for (int jj = 0; jj < 3; ++jj)
#pragma unroll
                for (int kk = 0; kk < 3; ++kk) fq[jj][kk] = Fd[(col0 + jj) * SS + 6 + kk];
#pragma unroll
            for (int ii = 0; ii < 6; ++ii)
#pragma unroll
                for (int jj = 0; jj < 3; ++jj)
#pragma unroll
                    for (int kk = 0; kk < 3; ++kk) P[ii][jj] += Uq[ii][kk] * fq[jj][kk];
        }
        {   // source sub-lane 3: U cols 9..11
            double Uq[6][3];
#pragma unroll
            for (int ii = 0; ii < 6; ++ii)
#pragma unroll
                for (int kk = 0; kk < 3; ++kk) Uq[ii][kk] = dpp64<0xFF>(U[ii][kk]);
            double fq[3][3];
#pragma unroll
            for (int jj = 0; jj < 3; ++jj)
#pragma unroll
                for (int kk = 0; kk < 3; ++kk) fq[jj][kk] = Fd[(col0 + jj) * SS + 9 + kk];
#pragma unroll
            for (int ii = 0; ii < 6; ++ii)
#pragma unroll
                for (int jj = 0; jj < 3; ++jj)
#pragma unroll
                    for (int kk = 0; kk < 3; ++kk) P[ii][jj] += Uq[ii][kk] * fq[jj][kk];
        }

        // ---------- y[n] via quad DPP butterfly ----------
        double y[MM];
#pragma unroll
        for (int n = 0; n < MM; ++n) {
            double py = Hd[n * SS + col0 + 0] * mvl[0]
                      + Hd[n * SS + col0 + 1] * mvl[1]
                      + Hd[n * SS + col0 + 2] * mvl[2];
            y[n] = qsum(py);
        }
        double ysel = (c & 2) ? ((c & 1) ? y[3] : y[2]) : ((c & 1) ? y[1] : y[0]);
        if (h == 0) outp[t * (BN * MM) + b * MM + c] = (float)ysel;

        float obc = obn;
        if (t + 1 < TT) obn = op[(t + 1) * MM];  // prefetch next obs

        double r0v = (double)dpp32<0x00>(obc) - y[0];
        double r1v = (double)dpp32<0x55>(obc) - y[1];
        double r2v = (double)dpp32<0xAA>(obc) - y[2];
        double r3v = (double)dpp32<0xFF>(obc) - y[3];

        // ---------- HP = H * P_prior: half-partial + xor-4 reduce ----------
        double HPl[MM][3];
#pragma unroll
        for (int n = 0; n < MM; ++n) {
            double h0 = 0.0, h1 = 0.0, h2 = 0.0;
#pragma unroll
            for (int s = 0; s < 6; ++s) {
                double hv = Hd[n * SS + hrow0 + s];
                h0 += hv * P[s][0]; h1 += hv * P[s][1]; h2 += hv * P[s][2];
            }
            HPl[n][0] = h0 + swz4(h0);
            HPl[n][1] = h1 + swz4(h1);
            HPl[n][2] = h2 + swz4(h2);
        }

        // ---------- innovation cov: local partial + quad butterfly ----------
        double Su[10];
        {
            int u = 0;
#pragma unroll
            for (int n = 0; n < MM; ++n)
#pragma unroll
                for (int t2 = 0; t2 < MM; ++t2) {
                    if (t2 < n) continue;
                    double acc = HPl[n][0] * Hd[t2 * SS + col0 + 0]
                               + HPl[n][1] * Hd[t2 * SS + col0 + 1]
                               + HPl[n][2] * Hd[t2 * SS + col0 + 2];
                    Su[u] = qsum(acc) + Rd[n * MM + t2];
                    ++u;
                }
        }
        double s00 = Su[0], s01 = Su[1], s02 = Su[2], s03 = Su[3];
        double s11 = Su[4], s12 = Su[5], s13 = Su[6];
        double s22 = Su[7], s23 = Su[8], s33 = Su[9];

        // ---------- symmetric 4x4 inverse via 2x2 Schur (fp64) ----------
        double ra   = 1.0 / (s00 * s11 - s01 * s01);
        double ai00 = s11 * ra, ai01 = -s01 * ra, ai11 = s00 * ra;
        double w00 = ai00 * s02 + ai01 * s12;
        double w01 = ai00 * s03 + ai01 * s13;
        double w10 = ai01 * s02 + ai11 * s12;
        double w11 = ai01 * s03 + ai11 * s13;
        double e00 = s22 - (s02 * w00 + s12 * w10);
        double e01 = s23 - (s02 * w01 + s12 * w11);
        double e11 = s33 - (s03 * w01 + s13 * w11);
        double rmm = 1.0 / (e00 * e11 - e01 * e01);
        double q22 = e11 * rmm, q23 = -e01 * rmm, q33 = e00 * rmm;
        double x00 = w00 * q22 + w01 * q23;
        double x01 = w00 * q23 + w01 * q33;
        double x10 = w10 * q22 + w11 * q23;
        double x11 = w10 * q23 + w11 * q33;
        double q00 = ai00 + x00 * w00 + x01 * w01;
        double q01 = ai01 + x00 * w10 + x01 * w11;
        double q11 = ai11 + x10 * w10 + x11 * w11;
        double Qi[MM][MM] = {
            { q00,  q01,  -x00, -x01 },
            { q01,  q11,  -x10, -x11 },
            { -x00, -x10,  q22,  q23 },
            { -x01, -x11,  q23,  q33 }
        };

        // ---------- z = Sinv r ; posterior mean ----------
        double z0 = Qi[0][0] * r0v + Qi[0][1] * r1v + Qi[0][2] * r2v + Qi[0][3] * r3v;
        double z1 = Qi[1][0] * r0v + Qi[1][1] * r1v + Qi[1][2] * r2v + Qi[1][3] * r3v;
        double z2 = Qi[2][0] * r0v + Qi[2][1] * r1v + Qi[2][2] * r2v + Qi[2][3] * r3v;
        double z3 = Qi[3][0] * r0v + Qi[3][1] * r1v + Qi[3][2] * r2v + Qi[3][3] * r3v;

        double pm[3];  // posterior mean, quad-own 3 states (3c+jj)
#pragma unroll
        for (int jj = 0; jj < 3; ++jj)
            pm[jj] = mvl[jj] + HPl[0][jj] * z0 + HPl[1][jj] * z1
                   + HPl[2][jj] * z2 + HPl[3][jj] * z3;

        // all-gather posterior mean via quad DPP (state 3q+jj on sub-lane q)
        m[0]  = dpp64<0x00>(pm[0]);  m[1]  = dpp64<0x00>(pm[1]);  m[2]  = dpp64<0x00>(pm[2]);
        m[3]  = dpp64<0x55>(pm[0]);  m[4]  = dpp64<0x55>(pm[1]);  m[5]  = dpp64<0x55>(pm[2]);
        m[6]  = dpp64<0xAA>(pm[0]);  m[7]  = dpp64<0xAA>(pm[1]);  m[8]  = dpp64<0xAA>(pm[2]);
        m[9]  = dpp64<0xFF>(pm[0]);  m[10] = dpp64<0xFF>(pm[1]);  m[11] = dpp64<0xFF>(pm[2]);

        // ---------- G = Sinv * HP (own cols) ----------
        double G[MM][3];
#pragma unroll
        for (int n = 0; n < MM; ++n)
#pragma unroll
            for (int jj = 0; jj < 3; ++jj)
                G[n][jj] = Qi[n][0] * HPl[0][jj] + Qi[n][1] * HPl[1][jj]
                         + Qi[n][2] * HPl[2][jj] + Qi[n][3] * HPl[3][jj];

        // ---------- cov update: P -= (HP)^T G, rows hrow0+ii ----------
        // HP[n][hrow0+ii]: ii 0..2 lives on quad sub-lane (h?2:0), ii 3..5 on (h?3:1).
        {
            double b0[MM][3], b2[MM][3];
#pragma unroll
            for (int n = 0; n < MM; ++n)
#pragma unroll
                for (int jj = 0; jj < 3; ++jj) {
                    b0[n][jj] = dpp64<0x00>(HPl[n][jj]);
                    b2[n][jj] = dpp64<0xAA>(HPl[n][jj]);
                }
            double bs[MM][3];
#pragma unroll
            for (int n = 0; n < MM; ++n)
#pragma unroll
                for (int ii = 0; ii < 3; ++ii)
                    bs[n][ii] = h ? b2[n][ii] : b0[n][ii];
#pragma unroll
            for (int ii = 0; ii < 3; ++ii)
#pragma unroll
                for (int jj = 0; jj < 3; ++jj)
                    P[ii][jj] -= bs[0][ii] * G[0][jj] + bs[1][ii] * G[1][jj]
                               + bs[2][ii] * G[2][jj] + bs[3][ii] * G[3][jj];
        }
        {
            double b1[MM][3], b3[MM][3];
#pragma unroll
            for (int n = 0; n < MM; ++n)
#pragma unroll
                for (int jj = 0; jj < 3; ++jj) {
                    b1[n][jj] = dpp64<0x55>(HPl[n][jj]);
                    b3[n][jj] = dpp64<0xFF>(HPl[n][jj]);
                }
            double bs[MM][3];
#pragma unroll
            for (int n = 0; n < MM; ++n)
#pragma unroll
                for (int ii = 0; ii < 3; ++ii)
                    bs[n][ii] = h ? b3[n][ii] : b1[n][ii];
#pragma unroll
            for (int ii = 0; ii < 3; ++ii)
#pragma unroll
                for (int jj = 0; jj < 3; ++jj)
                    P[3 + ii][jj] -= bs[0][ii] * G[0][jj] + bs[1][ii] * G[1][jj]
                                   + bs[2][ii] * G[2][jj] + bs[3][ii] * G[3][jj];
        }
    }
}

extern "C" void kernel_launch(void* const* d_in, const int* in_sizes, int n_in,
                              void* d_out, int out_size, void* d_ws, size_t ws_size,
                              hipStream_t stream) {
    const float* inp = (const float*)d_in[0];
    const float* F   = (const float*)d_in[1];
    const float* H   = (const float*)d_in[2];
    const float* Q   = (const float*)d_in[3];
    const float* R   = (const float*)d_in[4];
    const float* m0  = (const float*)d_in[5];
    const float* P0  = (const float*)d_in[6];
    float* out = (float*)d_out;

    dim3 grid((BN * 8) / BLOCK), block(BLOCK);
    hipLaunchKernelGGL(kf_kernel, grid, block, 0, stream,
                       inp, F, H, Q, R, m0, P0, out);
}

// Round 5
// 2839.328 us; speedup vs baseline: 1.1040x; 1.1040x over previous
//
#include <hip/hip_runtime.h>

#define BN 16384
#define TT 128
#define MM 4
#define SS 12
#define BLOCK 64

// R11 = R10 octet decomposition with the register budget PINNED.
// R10 post-mortem: __launch_bounds__(64,2) is only a MINIMUM waves/EU; the
// compiler chose a 128-VGPR budget (4 waves/EU capable) and spilled ~200
// VGPRs of live state to scratch -> 11 GB of scratch fetch, 3.1 ms.
// amdgpu_waves_per_eu(2,2) pins exactly 2 waves/EU -> 256-VGPR budget
// (mechanism verified in R8: the attribute sets the allocator budget).
//
// Octet layout: d = tid&7; h = d>>2 (row-half), c = d&3 (col-quad).
// Lane owns P rows [6h,6h+6) x cols [3c,3c+3).  Quads are h-uniform, so all
// quad DPP idioms (qsum butterflies, broadcasts) are unchanged. h-direction
// reductions (GEMM1 k-sum, HP) use ds_swizzle xor-4 -- register-to-register,
// no LDS scratch, no barriers anywhere in the t-loop.
// Small-M work (Su/inverse/z/G/mean) is replicated across the two halves.

// quad_perm ctrl: broadcast from sub-lane R -> R*0x55; xor1 -> 0xB1; xor2 -> 0x4E
template<int CTRL>
__device__ __forceinline__ float dpp32(float v) {
    union { int i; float f; } u, o;
    u.f = v;
    o.i = __builtin_amdgcn_update_dpp(0, u.i, CTRL, 0xF, 0xF, true);
    return o.f;
}
template<int CTRL>
__device__ __forceinline__ double dpp64(double v) {
    union { double d; int i[2]; } u, o;
    u.d = v;
    o.i[0] = __builtin_amdgcn_update_dpp(0, u.i[0], CTRL, 0xF, 0xF, true);
    o.i[1] = __builtin_amdgcn_update_dpp(0, u.i[1], CTRL, 0xF, 0xF, true);
    return o.d;
}
__device__ __forceinline__ double qsum(double v) {  // sum over the quad
    v += dpp64<0xB1>(v);
    v += dpp64<0x4E>(v);
    return v;
}
// lane <-> lane^4 exchange (flips h, keeps c). BitMode: xor=4, or=0, and=0x1F.
__device__ __forceinline__ double swz4(double v) {
    union { double d; int i[2]; } u, o;
    u.d = v;
    o.i[0] = __builtin_amdgcn_ds_swizzle(u.i[0], 0x101F);
    o.i[1] = __builtin_amdgcn_ds_swizzle(u.i[1], 0x101F);
    return o.d;
}

__global__ void
__attribute__((amdgpu_flat_work_group_size(BLOCK, BLOCK)))
__attribute__((amdgpu_waves_per_eu(2, 2)))
kf_kernel(
    const float* __restrict__ inp,   // [B][T][M]
    const float* __restrict__ Fm,    // [S][S]
    const float* __restrict__ Hm,    // [M][S]
    const float* __restrict__ Qm,    // [S][S]
    const float* __restrict__ Rm,    // [M][M]
    const float* __restrict__ m0p,   // [B][S]
    const float* __restrict__ P0p,   // [B][S][S]
    float* __restrict__ outp)        // [T][B][M]
{
    __shared__ double Fd[SS * SS];
    __shared__ double Hd[MM * SS];
    __shared__ double Qd[SS * SS];
    __shared__ double Rd[MM * MM];

    const int tid   = threadIdx.x;
    const int gid   = blockIdx.x * BLOCK + tid;
    const int b     = gid >> 3;        // series (8 lanes each)
    const int d     = tid & 7;
    const int h     = d >> 2;          // row-half of P
    const int c     = d & 3;           // quad sub-lane: cols {3c..3c+2}
    const int col0  = 3 * c;
    const int hrow0 = 6 * h;           // own row base
    const int orow0 = 6 - hrow0;       // other half's row base

    for (int i = tid; i < SS * SS; i += BLOCK) {
        Fd[i] = (double)Fm[i];
        Qd[i] = (double)Qm[i];
    }
    if (tid < MM * SS) Hd[tid] = (double)Hm[tid];
    if (tid < MM * MM) Rd[tid] = (double)Rm[tid];

    // persistent per-lane state: own 6x3 tile of P (posterior at loop top)
    double P[6][3];
#pragma unroll
    for (int ii = 0; ii < 6; ++ii)
#pragma unroll
        for (int jj = 0; jj < 3; ++jj)
            P[ii][jj] = (double)P0p[b * SS * SS + (hrow0 + ii) * SS + col0 + jj];

    // full replicated mean
    double m[SS];
#pragma unroll
    for (int s = 0; s < SS; ++s) m[s] = (double)m0p[b * SS + s];

    const float* op = inp + b * (TT * MM) + c;  // own measurement stream
    float obn = op[0];

    __syncthreads();  // constants in LDS ready (once)

#pragma unroll 1
    for (int t = 0; t < TT; ++t) {
        // ---------- GEMM1: U = F * P_post, k-split across halves ----------
        // pOwn: rows hrow0+ii (kept); pOth: rows orow0+ii (sent to partner).
        double pOwn[6][3], pOth[6][3];
#pragma unroll
        for (int ii = 0; ii < 6; ++ii) {
#pragma unroll
            for (int jj = 0; jj < 3; ++jj) { pOwn[ii][jj] = 0.0; pOth[ii][jj] = 0.0; }
#pragma unroll
            for (int s = 0; s < 6; ++s) {
                double fo = Fd[(hrow0 + ii) * SS + hrow0 + s];
                double ft = Fd[(orow0 + ii) * SS + hrow0 + s];
#pragma unroll
                for (int jj = 0; jj < 3; ++jj) {
                    pOwn[ii][jj] += fo * P[s][jj];
                    pOth[ii][jj] += ft * P[s][jj];
                }
            }
        }
        // U rows [hrow0,hrow0+6) x own cols: own partial + partner's complement
        double U[6][3];
#pragma unroll
        for (int ii = 0; ii < 6; ++ii)
#pragma unroll
            for (int jj = 0; jj < 3; ++jj)
                U[ii][jj] = pOwn[ii][jj] + swz4(pOth[ii][jj]);

        // ---------- own 3 quad-rows of predicted mean: F[3c+jj,:] . m ----------
        double mvl[3];
#pragma unroll
        for (int jj = 0; jj < 3; ++jj) {
            double a = 0.0;
#pragma unroll
            for (int s = 0; s < SS; ++s) a += Fd[(col0 + jj) * SS + s] * m[s];
            mvl[jj] = a;
        }

        // ---------- GEMM2: P <- Q + U * F^T (prior, in place) ----------
        // quad all-gather of U columns via DPP broadcasts (quad is h-uniform).
#pragma unroll
        for (int ii = 0; ii < 6; ++ii)
#pragma unroll
            for (int jj = 0; jj < 3; ++jj)
                P[ii][jj] = Qd[(hrow0 + ii) * SS + col0 + jj];

        {   // source sub-lane 0: U cols 0..2
            double Uq[6][3];
#pragma unroll
            for (int ii = 0; ii < 6; ++ii)
#pragma unroll
                for (int kk = 0; kk < 3; ++kk) Uq[ii][kk] = dpp64<0x00>(U[ii][kk]);
            double fq[3][3];
#pragma unroll
            for (int jj = 0; jj < 3; ++jj)
#pragma unroll
                for (int kk = 0; kk < 3; ++kk) fq[jj][kk] = Fd[(col0 + jj) * SS + 0 + kk];
#pragma unroll
            for (int ii = 0; ii < 6; ++ii)
#pragma unroll
                for (int jj = 0; jj < 3; ++jj)
#pragma unroll
                    for (int kk = 0; kk < 3; ++kk) P[ii][jj] += Uq[ii][kk] * fq[jj][kk];
        }
        {   // source sub-lane 1: U cols 3..5
            double Uq[6][3];
#pragma unroll
            for (int ii = 0; ii < 6; ++ii)
#pragma unroll
                for (int kk = 0; kk < 3; ++kk) Uq[ii][kk] = dpp64<0x55>(U[ii][kk]);
            double fq[3][3];
#pragma unroll
            for (int jj = 0; jj < 3; ++jj)
#pragma unroll
                for (int kk = 0; kk < 3; ++kk) fq[jj][kk] = Fd[(col0 + jj) * SS + 3 + kk];
#pragma unroll
            for (int ii = 0; ii < 6; ++ii)
#pragma unroll
                for (int jj = 0; jj < 3; ++jj)
#pragma unroll
                    for (int kk = 0; kk < 3; ++kk) P[ii][jj] += Uq[ii][kk] * fq[jj][kk];
        }
        {   // source sub-lane 2: U cols 6..8
            double Uq[6][3];
#pragma unroll
            for (int ii = 0; ii < 6; ++ii)
#pragma unroll
                for (int kk = 0; kk < 3; ++kk) Uq[ii][kk] = dpp64<0xAA>(U[ii][kk]);
            double fq[3][3];
#pragma unroll
            for (int jj = 0; jj < 3; ++jj)
#pragma unroll
                for (int kk = 0; kk < 3; ++kk) fq[jj][kk] = Fd[(col0 + jj) * SS + 6 + kk];
#pragma unroll
            for (int ii = 0; ii < 6; ++ii)
#pragma unroll
                for (int jj = 0; jj < 3; ++jj)
#pragma unroll
                    for (int kk = 0; kk < 3; ++kk) P[ii][jj] += Uq[ii][kk] * fq[jj][kk];
        }
        {   // source sub-lane 3: U cols 9..11
            double Uq[6][3];
#pragma unroll
            for (int ii = 0; ii < 6; ++ii)
#pragma unroll
                for (int kk = 0; kk < 3; ++kk) Uq[ii][kk] = dpp64<0xFF>(U[ii][kk]);
            double fq[3][3];
#pragma unroll
            for (int jj = 0; jj < 3; ++jj)
#pragma unroll
                for (int kk = 0; kk < 3; ++kk) fq[jj][kk] = Fd[(col0 + jj) * SS + 9 + kk];
#pragma unroll
            for (int ii = 0; ii < 6; ++ii)
#pragma unroll
                for (int jj = 0; jj < 3; ++jj)
#pragma unroll
                    for (int kk = 0; kk < 3; ++kk) P[ii][jj] += Uq[ii][kk] * fq[jj][kk];
        }

        // ---------- y[n] via quad DPP butterfly ----------
        double y[MM];
#pragma unroll
        for (int n = 0; n < MM; ++n) {
            double py = Hd[n * SS + col0 + 0] * mvl[0]
                      + Hd[n * SS + col0 + 1] * mvl[1]
                      + Hd[n * SS + col0 + 2] * mvl[2];
            y[n] = qsum(py);
        }
        double ysel = (c & 2) ? ((c & 1) ? y[3] : y[2]) : ((c & 1) ? y[1] : y[0]);
        if (h == 0) outp[t * (BN * MM) + b * MM + c] = (float)ysel;

        float obc = obn;
        if (t + 1 < TT) obn = op[(t + 1) * MM];  // prefetch next obs

        double r0v = (double)dpp32<0x00>(obc) - y[0];
        double r1v = (double)dpp32<0x55>(obc) - y[1];
        double r2v = (double)dpp32<0xAA>(obc) - y[2];
        double r3v = (double)dpp32<0xFF>(obc) - y[3];

        // ---------- HP = H * P_prior: half-partial + xor-4 reduce ----------
        double HPl[MM][3];
#pragma unroll
        for (int n = 0; n < MM; ++n) {
            double h0 = 0.0, h1 = 0.0, h2 = 0.0;
#pragma unroll
            for (int s = 0; s < 6; ++s) {
                double hv = Hd[n * SS + hrow0 + s];
                h0 += hv * P[s][0]; h1 += hv * P[s][1]; h2 += hv * P[s][2];
            }
            HPl[n][0] = h0 + swz4(h0);
            HPl[n][1] = h1 + swz4(h1);
            HPl[n][2] = h2 + swz4(h2);
        }

        // ---------- innovation cov: local partial + quad butterfly ----------
        double Su[10];
        {
            int u = 0;
#pragma unroll
            for (int n = 0; n < MM; ++n)
#pragma unroll
                for (int t2 = 0; t2 < MM; ++t2) {
                    if (t2 < n) continue;
                    double acc = HPl[n][0] * Hd[t2 * SS + col0 + 0]
                               + HPl[n][1] * Hd[t2 * SS + col0 + 1]
                               + HPl[n][2] * Hd[t2 * SS + col0 + 2];
                    Su[u] = qsum(acc) + Rd[n * MM + t2];
                    ++u;
                }
        }
        double s00 = Su[0], s01 = Su[1], s02 = Su[2], s03 = Su[3];
        double s11 = Su[4], s12 = Su[5], s13 = Su[6];
        double s22 = Su[7], s23 = Su[8], s33 = Su[9];

        // ---------- symmetric 4x4 inverse via 2x2 Schur (fp64) ----------
        double ra   = 1.0 / (s00 * s11 - s01 * s01);
        double ai00 = s11 * ra, ai01 = -s01 * ra, ai11 = s00 * ra;
        double w00 = ai00 * s02 + ai01 * s12;
        double w01 = ai00 * s03 + ai01 * s13;
        double w10 = ai01 * s02 + ai11 * s12;
        double w11 = ai01 * s03 + ai11 * s13;
        double e00 = s22 - (s02 * w00 + s12 * w10);
        double e01 = s23 - (s02 * w01 + s12 * w11);
        double e11 = s33 - (s03 * w01 + s13 * w11);
        double rmm = 1.0 / (e00 * e11 - e01 * e01);
        double q22 = e11 * rmm, q23 = -e01 * rmm, q33 = e00 * rmm;
        double x00 = w00 * q22 + w01 * q23;
        double x01 = w00 * q23 + w01 * q33;
        double x10 = w10 * q22 + w11 * q23;
        double x11 = w10 * q23 + w11 * q33;
        double q00 = ai00 + x00 * w00 + x01 * w01;
        double q01 = ai01 + x00 * w10 + x01 * w11;
        double q11 = ai11 + x10 * w10 + x11 * w11;
        double Qi[MM][MM] = {
            { q00,  q01,  -x00, -x01 },
            { q01,  q11,  -x10, -x11 },
            { -x00, -x10,  q22,  q23 },
            { -x01, -x11,  q23,  q33 }
        };

        // ---------- z = Sinv r ; posterior mean ----------
        double z0 = Qi[0][0] * r0v + Qi[0][1] * r1v + Qi[0][2] * r2v + Qi[0][3] * r3v;
        double z1 = Qi[1][0] * r0v + Qi[1][1] * r1v + Qi[1][2] * r2v + Qi[1][3] * r3v;
        double z2 = Qi[2][0] * r0v + Qi[2][1] * r1v + Qi[2][2] * r2v + Qi[2][3] * r3v;
        double z3 = Qi[3][0] * r0v + Qi[3][1] * r1v + Qi[3][2] * r2v + Qi[3][3] * r3v;

        double pm[3];  // posterior mean, quad-own 3 states (3c+jj)
#pragma unroll
        for (int jj = 0; jj < 3; ++jj)
            pm[jj] = mvl[jj] + HPl[0][jj] * z0 + HPl[1][jj] * z1
                   + HPl[2][jj] * z2 + HPl[3][jj] * z3;

        // all-gather posterior mean via quad DPP (state 3q+jj on sub-lane q)
        m[0]  = dpp64<0x00>(pm[0]);  m[1]  = dpp64<0x00>(pm[1]);  m[2]  = dpp64<0x00>(pm[2]);
        m[3]  = dpp64<0x55>(pm[0]);  m[4]  = dpp64<0x55>(pm[1]);  m[5]  = dpp64<0x55>(pm[2]);
        m[6]  = dpp64<0xAA>(pm[0]);  m[7]  = dpp64<0xAA>(pm[1]);  m[8]  = dpp64<0xAA>(pm[2]);
        m[9]  = dpp64<0xFF>(pm[0]);  m[10] = dpp64<0xFF>(pm[1]);  m[11] = dpp64<0xFF>(pm[2]);

        // ---------- G = Sinv * HP (own cols) ----------
        double G[MM][3];
#pragma unroll
        for (int n = 0; n < MM; ++n)
#pragma unroll
            for (int jj = 0; jj < 3; ++jj)
                G[n][jj] = Qi[n][0] * HPl[0][jj] + Qi[n][1] * HPl[1][jj]
                         + Qi[n][2] * HPl[2][jj] + Qi[n][3] * HPl[3][jj];

        // ---------- cov update: P -= (HP)^T G, rows hrow0+ii ----------
        // HP[n][hrow0+ii]: ii 0..2 lives on quad sub-lane (h?2:0), ii 3..5 on (h?3:1).
        {
            double b0[MM][3], b2[MM][3];
#pragma unroll
            for (int n = 0; n < MM; ++n)
#pragma unroll
                for (int jj = 0; jj < 3; ++jj) {
                    b0[n][jj] = dpp64<0x00>(HPl[n][jj]);
                    b2[n][jj] = dpp64<0xAA>(HPl[n][jj]);
                }
            double bs[MM][3];
#pragma unroll
            for (int n = 0; n < MM; ++n)
#pragma unroll
                for (int ii = 0; ii < 3; ++ii)
                    bs[n][ii] = h ? b2[n][ii] : b0[n][ii];
#pragma unroll
            for (int ii = 0; ii < 3; ++ii)
#pragma unroll
                for (int jj = 0; jj < 3; ++jj)
                    P[ii][jj] -= bs[0][ii] * G[0][jj] + bs[1][ii] * G[1][jj]
                               + bs[2][ii] * G[2][jj] + bs[3][ii] * G[3][jj];
        }
        {
            double b1[MM][3], b3[MM][3];
#pragma unroll
            for (int n = 0; n < MM; ++n)
#pragma unroll
                for (int jj = 0; jj < 3; ++jj) {
                    b1[n][jj] = dpp64<0x55>(HPl[n][jj]);
                    b3[n][jj] = dpp64<0xFF>(HPl[n][jj]);
                }
            double bs[MM][3];
#pragma unroll
            for (int n = 0; n < MM; ++n)
#pragma unroll
                for (int ii = 0; ii < 3; ++ii)
                    bs[n][ii] = h ? b3[n][ii] : b1[n][ii];
#pragma unroll
            for (int ii = 0; ii < 3; ++ii)
#pragma unroll
                for (int jj = 0; jj < 3; ++jj)
                    P[3 + ii][jj] -= bs[0][ii] * G[0][jj] + bs[1][ii] * G[1][jj]
                                   + bs[2][ii] * G[2][jj] + bs[3][ii] * G[3][jj];
        }
    }
}

extern "C" void kernel_launch(void* const* d_in, const int* in_sizes, int n_in,
                              void* d_out, int out_size, void* d_ws, size_t ws_size,
                              hipStream_t stream) {
    const float* inp = (const float*)d_in[0];
    const float* F   = (const float*)d_in[1];
    const float* H   = (const float*)d_in[2];
    const float* Q   = (const float*)d_in[3];
    const float* R   = (const float*)d_in[4];
    const float* m0  = (const float*)d_in[5];
    const float* P0  = (const float*)d_in[6];
    float* out = (float*)d_out;

    dim3 grid((BN * 8) / BLOCK), block(BLOCK);
    hipLaunchKernelGGL(kf_kernel, grid, block, 0, stream,
                       inp, F, H, Q, R, m0, P0, out);
}

// Round 6
// 1375.713 us; speedup vs baseline: 2.2784x; 2.0639x over previous
//
#include <hip/hip_runtime.h>

#define BN 16384
#define TT 128
#define MM 4
#define SS 12
#define BLOCK 64

// R12 = R10/R11 octet decomposition, register budget finally correct.
// Toolchain finding (R8/R10/R11): the compiler budgets VGPRs as 256/min_waves
// (it models a 256-reg pool/SIMD), but gfx950 HW has a 512-reg pool -- waves
// with VGPR in (128,256] still get 2 waves/SIMD (m69 occupancy steps).
// So: ask the COMPILER for 1 wave/EU (-> 256-VGPR budget, verified R8) and
// let the HARDWARE co-schedule 2 waves/SIMD from the 2048-wave grid.
// Octet peak liveness ~200 VGPR -> no spill expected.
//
// Octet layout: d = tid&7; h = d>>2 (row-half), c = d&3 (col-quad).
// Lane owns P rows [6h,6h+6) x cols [3c,3c+3).  Quads are h-uniform, so all
// quad DPP idioms (qsum butterflies, broadcasts) are unchanged. h-direction
// reductions (GEMM1 k-sum, HP) use ds_swizzle xor-4 -- register-to-register,
// no LDS scratch, no barriers anywhere in the t-loop.
// Small-M work (Su/inverse/z/G/mean) is replicated across the two halves.

// quad_perm ctrl: broadcast from sub-lane R -> R*0x55; xor1 -> 0xB1; xor2 -> 0x4E
template<int CTRL>
__device__ __forceinline__ float dpp32(float v) {
    union { int i; float f; } u, o;
    u.f = v;
    o.i = __builtin_amdgcn_update_dpp(0, u.i, CTRL, 0xF, 0xF, true);
    return o.f;
}
template<int CTRL>
__device__ __forceinline__ double dpp64(double v) {
    union { double d; int i[2]; } u, o;
    u.d = v;
    o.i[0] = __builtin_amdgcn_update_dpp(0, u.i[0], CTRL, 0xF, 0xF, true);
    o.i[1] = __builtin_amdgcn_update_dpp(0, u.i[1], CTRL, 0xF, 0xF, true);
    return o.d;
}
__device__ __forceinline__ double qsum(double v) {  // sum over the quad
    v += dpp64<0xB1>(v);
    v += dpp64<0x4E>(v);
    return v;
}
// lane <-> lane^4 exchange (flips h, keeps c). BitMode: xor=4, or=0, and=0x1F.
__device__ __forceinline__ double swz4(double v) {
    union { double d; int i[2]; } u, o;
    u.d = v;
    o.i[0] = __builtin_amdgcn_ds_swizzle(u.i[0], 0x101F);
    o.i[1] = __builtin_amdgcn_ds_swizzle(u.i[1], 0x101F);
    return o.d;
}

__global__ void
__attribute__((amdgpu_flat_work_group_size(BLOCK, BLOCK)))
__attribute__((amdgpu_waves_per_eu(1, 1)))
kf_kernel(
    const float* __restrict__ inp,   // [B][T][M]
    const float* __restrict__ Fm,    // [S][S]
    const float* __restrict__ Hm,    // [M][S]
    const float* __restrict__ Qm,    // [S][S]
    const float* __restrict__ Rm,    // [M][M]
    const float* __restrict__ m0p,   // [B][S]
    const float* __restrict__ P0p,   // [B][S][S]
    float* __restrict__ outp)        // [T][B][M]
{
    __shared__ double Fd[SS * SS];
    __shared__ double Hd[MM * SS];
    __shared__ double Qd[SS * SS];
    __shared__ double Rd[MM * MM];

    const int tid   = threadIdx.x;
    const int gid   = blockIdx.x * BLOCK + tid;
    const int b     = gid >> 3;        // series (8 lanes each)
    const int d     = tid & 7;
    const int h     = d >> 2;          // row-half of P
    const int c     = d & 3;           // quad sub-lane: cols {3c..3c+2}
    const int col0  = 3 * c;
    const int hrow0 = 6 * h;           // own row base
    const int orow0 = 6 - hrow0;       // other half's row base

    for (int i = tid; i < SS * SS; i += BLOCK) {
        Fd[i] = (double)Fm[i];
        Qd[i] = (double)Qm[i];
    }
    if (tid < MM * SS) Hd[tid] = (double)Hm[tid];
    if (tid < MM * MM) Rd[tid] = (double)Rm[tid];

    // persistent per-lane state: own 6x3 tile of P (posterior at loop top)
    double P[6][3];
#pragma unroll
    for (int ii = 0; ii < 6; ++ii)
#pragma unroll
        for (int jj = 0; jj < 3; ++jj)
            P[ii][jj] = (double)P0p[b * SS * SS + (hrow0 + ii) * SS + col0 + jj];

    // full replicated mean
    double m[SS];
#pragma unroll
    for (int s = 0; s < SS; ++s) m[s] = (double)m0p[b * SS + s];

    const float* op = inp + b * (TT * MM) + c;  // own measurement stream
    float obn = op[0];

    __syncthreads();  // constants in LDS ready (once)

#pragma unroll 1
    for (int t = 0; t < TT; ++t) {
        // ---------- GEMM1: U = F * P_post, k-split across halves ----------
        // pOwn: rows hrow0+ii (kept); pOth: rows orow0+ii (sent to partner).
        double pOwn[6][3], pOth[6][3];
#pragma unroll
        for (int ii = 0; ii < 6; ++ii) {
#pragma unroll
            for (int jj = 0; jj < 3; ++jj) { pOwn[ii][jj] = 0.0; pOth[ii][jj] = 0.0; }
#pragma unroll
            for (int s = 0; s < 6; ++s) {
                double fo = Fd[(hrow0 + ii) * SS + hrow0 + s];
                double ft = Fd[(orow0 + ii) * SS + hrow0 + s];
#pragma unroll
                for (int jj = 0; jj < 3; ++jj) {
                    pOwn[ii][jj] += fo * P[s][jj];
                    pOth[ii][jj] += ft * P[s][jj];
                }
            }
        }
        // U rows [hrow0,hrow0+6) x own cols: own partial + partner's complement
        double U[6][3];
#pragma unroll
        for (int ii = 0; ii < 6; ++ii)
#pragma unroll
            for (int jj = 0; jj < 3; ++jj)
                U[ii][jj] = pOwn[ii][jj] + swz4(pOth[ii][jj]);

        // ---------- own 3 quad-rows of predicted mean: F[3c+jj,:] . m ----------
        double mvl[3];
#pragma unroll
        for (int jj = 0; jj < 3; ++jj) {
            double a = 0.0;
#pragma unroll
            for (int s = 0; s < SS; ++s) a += Fd[(col0 + jj) * SS + s] * m[s];
            mvl[jj] = a;
        }

        // ---------- GEMM2: P <- Q + U * F^T (prior, in place) ----------
        // quad all-gather of U columns via DPP broadcasts (quad is h-uniform).
#pragma unroll
        for (int ii = 0; ii < 6; ++ii)
#pragma unroll
            for (int jj = 0; jj < 3; ++jj)
                P[ii][jj] = Qd[(hrow0 + ii) * SS + col0 + jj];

        {   // source sub-lane 0: U cols 0..2
            double Uq[6][3];
#pragma unroll
            for (int ii = 0; ii < 6; ++ii)
#pragma unroll
                for (int kk = 0; kk < 3; ++kk) Uq[ii][kk] = dpp64<0x00>(U[ii][kk]);
            double fq[3][3];
#pragma unroll
            for (int jj = 0; jj < 3; ++jj)
#pragma unroll
                for (int kk = 0; kk < 3; ++kk) fq[jj][kk] = Fd[(col0 + jj) * SS + 0 + kk];
#pragma unroll
            for (int ii = 0; ii < 6; ++ii)
#pragma unroll
                for (int jj = 0; jj < 3; ++jj)
#pragma unroll
                    for (int kk = 0; kk < 3; ++kk) P[ii][jj] += Uq[ii][kk] * fq[jj][kk];
        }
        {   // source sub-lane 1: U cols 3..5
            double Uq[6][3];
#pragma unroll
            for (int ii = 0; ii < 6; ++ii)
#pragma unroll
                for (int kk = 0; kk < 3; ++kk) Uq[ii][kk] = dpp64<0x55>(U[ii][kk]);
            double fq[3][3];
#pragma unroll
            for (int jj = 0; jj < 3; ++jj)
#pragma unroll
                for (int kk = 0; kk < 3; ++kk) fq[jj][kk] = Fd[(col0 + jj) * SS + 3 + kk];
#pragma unroll
            for (int ii = 0; ii < 6; ++ii)
#pragma unroll
                for (int jj = 0; jj < 3; ++jj)
#pragma unroll
                    for (int kk = 0; kk < 3; ++kk) P[ii][jj] += Uq[ii][kk] * fq[jj][kk];
        }
        {   // source sub-lane 2: U cols 6..8
            double Uq[6][3];
#pragma unroll
            for (int ii = 0; ii < 6; ++ii)
#pragma unroll
                for (int kk = 0; kk < 3; ++kk) Uq[ii][kk] = dpp64<0xAA>(U[ii][kk]);
            double fq[3][3];
#pragma unroll
            for (int jj = 0; jj < 3; ++jj)
#pragma unroll
                for (int kk = 0; kk < 3; ++kk) fq[jj][kk] = Fd[(col0 + jj) * SS + 6 + kk];
#pragma unroll
            for (int ii = 0; ii < 6; ++ii)
#pragma unroll
                for (int jj = 0; jj < 3; ++jj)
#pragma unroll
                    for (int kk = 0; kk < 3; ++kk) P[ii][jj] += Uq[ii][kk] * fq[jj][kk];
        }
        {   // source sub-lane 3: U cols 9..11
            double Uq[6][3];
#pragma unroll
            for (int ii = 0; ii < 6; ++ii)
#pragma unroll
                for (int kk = 0; kk < 3; ++kk) Uq[ii][kk] = dpp64<0xFF>(U[ii][kk]);
            double fq[3][3];
#pragma unroll
            for (int jj = 0; jj < 3; ++jj)
#pragma unroll
                for (int kk = 0; kk < 3; ++kk) fq[jj][kk] = Fd[(col0 + jj) * SS + 9 + kk];
#pragma unroll
            for (int ii = 0; ii < 6; ++ii)
#pragma unroll
                for (int jj = 0; jj < 3; ++jj)
#pragma unroll
                    for (int kk = 0; kk < 3; ++kk) P[ii][jj] += Uq[ii][kk] * fq[jj][kk];
        }

        // ---------- y[n] via quad DPP butterfly ----------
        double y[MM];
#pragma unroll
        for (int n = 0; n < MM; ++n) {
            double py = Hd[n * SS + col0 + 0] * mvl[0]
                      + Hd[n * SS + col0 + 1] * mvl[1]
                      + Hd[n * SS + col0 + 2] * mvl[2];
            y[n] = qsum(py);
        }
        double ysel = (c & 2) ? ((c & 1) ? y[3] : y[2]) : ((c & 1) ? y[1] : y[0]);
        if (h == 0) outp[t * (BN * MM) + b * MM + c] = (float)ysel;

        float obc = obn;
        if (t + 1 < TT) obn = op[(t + 1) * MM];  // prefetch next obs

        double r0v = (double)dpp32<0x00>(obc) - y[0];
        double r1v = (double)dpp32<0x55>(obc) - y[1];
        double r2v = (double)dpp32<0xAA>(obc) - y[2];
        double r3v = (double)dpp32<0xFF>(obc) - y[3];

        // ---------- HP = H * P_prior: half-partial + xor-4 reduce ----------
        double HPl[MM][3];
#pragma unroll
        for (int n = 0; n < MM; ++n) {
            double h0 = 0.0, h1 = 0.0, h2 = 0.0;
#pragma unroll
            for (int s = 0; s < 6; ++s) {
                double hv = Hd[n * SS + hrow0 + s];
                h0 += hv * P[s][0]; h1 += hv * P[s][1]; h2 += hv * P[s][2];
            }
            HPl[n][0] = h0 + swz4(h0);
            HPl[n][1] = h1 + swz4(h1);
            HPl[n][2] = h2 + swz4(h2);
        }

        // ---------- innovation cov: local partial + quad butterfly ----------
        double Su[10];
        {
            int u = 0;
#pragma unroll
            for (int n = 0; n < MM; ++n)
#pragma unroll
                for (int t2 = 0; t2 < MM; ++t2) {
                    if (t2 < n) continue;
                    double acc = HPl[n][0] * Hd[t2 * SS + col0 + 0]
                               + HPl[n][1] * Hd[t2 * SS + col0 + 1]
                               + HPl[n][2] * Hd[t2 * SS + col0 + 2];
                    Su[u] = qsum(acc) + Rd[n * MM + t2];
                    ++u;
                }
        }
        double s00 = Su[0], s01 = Su[1], s02 = Su[2], s03 = Su[3];
        double s11 = Su[4], s12 = Su[5], s13 = Su[6];
        double s22 = Su[7], s23 = Su[8], s33 = Su[9];

        // ---------- symmetric 4x4 inverse via 2x2 Schur (fp64) ----------
        double ra   = 1.0 / (s00 * s11 - s01 * s01);
        double ai00 = s11 * ra, ai01 = -s01 * ra, ai11 = s00 * ra;
        double w00 = ai00 * s02 + ai01 * s12;
        double w01 = ai00 * s03 + ai01 * s13;
        double w10 = ai01 * s02 + ai11 * s12;
        double w11 = ai01 * s03 + ai11 * s13;
        double e00 = s22 - (s02 * w00 + s12 * w10);
        double e01 = s23 - (s02 * w01 + s12 * w11);
        double e11 = s33 - (s03 * w01 + s13 * w11);
        double rmm = 1.0 / (e00 * e11 - e01 * e01);
        double q22 = e11 * rmm, q23 = -e01 * rmm, q33 = e00 * rmm;
        double x00 = w00 * q22 + w01 * q23;
        double x01 = w00 * q23 + w01 * q33;
        double x10 = w10 * q22 + w11 * q23;
        double x11 = w10 * q23 + w11 * q33;
        double q00 = ai00 + x00 * w00 + x01 * w01;
        double q01 = ai01 + x00 * w10 + x01 * w11;
        double q11 = ai11 + x10 * w10 + x11 * w11;
        double Qi[MM][MM] = {
            { q00,  q01,  -x00, -x01 },
            { q01,  q11,  -x10, -x11 },
            { -x00, -x10,  q22,  q23 },
            { -x01, -x11,  q23,  q33 }
        };

        // ---------- z = Sinv r ; posterior mean ----------
        double z0 = Qi[0][0] * r0v + Qi[0][1] * r1v + Qi[0][2] * r2v + Qi[0][3] * r3v;
        double z1 = Qi[1][0] * r0v + Qi[1][1] * r1v + Qi[1][2] * r2v + Qi[1][3] * r3v;
        double z2 = Qi[2][0] * r0v + Qi[2][1] * r1v + Qi[2][2] * r2v + Qi[2][3] * r3v;
        double z3 = Qi[3][0] * r0v + Qi[3][1] * r1v + Qi[3][2] * r2v + Qi[3][3] * r3v;

        double pm[3];  // posterior mean, quad-own 3 states (3c+jj)
#pragma unroll
        for (int jj = 0; jj < 3; ++jj)
            pm[jj] = mvl[jj] + HPl[0][jj] * z0 + HPl[1][jj] * z1
                   + HPl[2][jj] * z2 + HPl[3][jj] * z3;

        // all-gather posterior mean via quad DPP (state 3q+jj on sub-lane q)
        m[0]  = dpp64<0x00>(pm[0]);  m[1]  = dpp64<0x00>(pm[1]);  m[2]  = dpp64<0x00>(pm[2]);
        m[3]  = dpp64<0x55>(pm[0]);  m[4]  = dpp64<0x55>(pm[1]);  m[5]  = dpp64<0x55>(pm[2]);
        m[6]  = dpp64<0xAA>(pm[0]);  m[7]  = dpp64<0xAA>(pm[1]);  m[8]  = dpp64<0xAA>(pm[2]);
        m[9]  = dpp64<0xFF>(pm[0]);  m[10] = dpp64<0xFF>(pm[1]);  m[11] = dpp64<0xFF>(pm[2]);

        // ---------- G = Sinv * HP (own cols) ----------
        double G[MM][3];
#pragma unroll
        for (int n = 0; n < MM; ++n)
#pragma unroll
            for (int jj = 0; jj < 3; ++jj)
                G[n][jj] = Qi[n][0] * HPl[0][jj] + Qi[n][1] * HPl[1][jj]
                         + Qi[n][2] * HPl[2][jj] + Qi[n][3] * HPl[3][jj];

        // ---------- cov update: P -= (HP)^T G, rows hrow0+ii ----------
        // HP[n][hrow0+ii]: ii 0..2 lives on quad sub-lane (h?2:0), ii 3..5 on (h?3:1).
        {
            double b0[MM][3], b2[MM][3];
#pragma unroll
            for (int n = 0; n < MM; ++n)
#pragma unroll
                for (int jj = 0; jj < 3; ++jj) {
                    b0[n][jj] = dpp64<0x00>(HPl[n][jj]);
                    b2[n][jj] = dpp64<0xAA>(HPl[n][jj]);
                }
            double bs[MM][3];
#pragma unroll
            for (int n = 0; n < MM; ++n)
#pragma unroll
                for (int ii = 0; ii < 3; ++ii)
                    bs[n][ii] = h ? b2[n][ii] : b0[n][ii];
#pragma unroll
            for (int ii = 0; ii < 3; ++ii)
#pragma unroll
                for (int jj = 0; jj < 3; ++jj)
                    P[ii][jj] -= bs[0][ii] * G[0][jj] + bs[1][ii] * G[1][jj]
                               + bs[2][ii] * G[2][jj] + bs[3][ii] * G[3][jj];
        }
        {
            double b1[MM][3], b3[MM][3];
#pragma unroll
            for (int n = 0; n < MM; ++n)
#pragma unroll
                for (int jj = 0; jj < 3; ++jj) {
                    b1[n][jj] = dpp64<0x55>(HPl[n][jj]);
                    b3[n][jj] = dpp64<0xFF>(HPl[n][jj]);
                }
            double bs[MM][3];
#pragma unroll
            for (int n = 0; n < MM; ++n)
#pragma unroll
                for (int ii = 0; ii < 3; ++ii)
                    bs[n][ii] = h ? b3[n][ii] : b1[n][ii];
#pragma unroll
            for (int ii = 0; ii < 3; ++ii)
#pragma unroll
                for (int jj = 0; jj < 3; ++jj)
                    P[3 + ii][jj] -= bs[0][ii] * G[0][jj] + bs[1][ii] * G[1][jj]
                                   + bs[2][ii] * G[2][jj] + bs[3][ii] * G[3][jj];
        }
    }
}

extern "C" void kernel_launch(void* const* d_in, const int* in_sizes, int n_in,
                              void* d_out, int out_size, void* d_ws, size_t ws_size,
                              hipStream_t stream) {
    const float* inp = (const float*)d_in[0];
    const float* F   = (const float*)d_in[1];
    const float* H   = (const float*)d_in[2];
    const float* Q   = (const float*)d_in[3];
    const float* R   = (const float*)d_in[4];
    const float* m0  = (const float*)d_in[5];
    const float* P0  = (const float*)d_in[6];
    float* out = (float*)d_out;

    dim3 grid((BN * 8) / BLOCK), block(BLOCK);
    hipLaunchKernelGGL(kf_kernel, grid, block, 0, stream,
                       inp, F, H, Q, R, m0, P0, out);
}